// Round 14
// baseline (178.927 us; speedup 1.0000x reference)
//
#include <hip/hip_runtime.h>
#include <hip/hip_fp16.h>
#include <math.h>

// FourierCrossAttention: B=16, L=S=2048, H=8, E=O=64, M=64 (first 64 rfft modes)
// Pipeline: tables(fused) -> MFMA bf16 3-product DFT [K-split x2, + W-transpose blocks z=3]
//           -> fused(reduce+QK+tanh+QKV) -> QKVW(x1024, bf16 W) -> MFMA fp16 iDFT (/1024)
// R14: k_wt folded into k_gemm grid (z==3 backfills gemm tail); Wt packed bf16 re|im
// (halves W read traffic); k_qkvw e-loop unrolled x8. k_gemm z<3 path identical to R13.

#define NB 16
#define NL 2048
#define NH 8
#define NE 64
#define NM 64
#define NHE 512  // H*E

typedef unsigned short ushort_t;
typedef __attribute__((ext_vector_type(8))) short short8;
typedef __attribute__((ext_vector_type(8))) _Float16 half8;
typedef __attribute__((ext_vector_type(4))) float f32x4;

__device__ inline void gld_lds16(const void* g, void* l) {
    __builtin_amdgcn_global_load_lds((const __attribute__((address_space(1))) unsigned int*)g,
                                     (__attribute__((address_space(3))) unsigned int*)l, 16, 0, 0);
}

__device__ inline unsigned bf16_rne_bits(float v) {
    unsigned b = __float_as_uint(v);
    return (b + 0x7fffu + ((b >> 16) & 1u)) >> 16;
}

// ---------------- K0: fused twiddle tables (DFT hi/lo bf16 + iDFT fp16), frag order ----------
__global__ __launch_bounds__(256) void k_tables(ushort_t* __restrict__ Twh,
                                                ushort_t* __restrict__ Twl,
                                                ushort_t* __restrict__ Ih) {
    const int blk = blockIdx.x;
    if (blk < 1024) {
        int i = blk * 256 + threadIdx.x;  // over 64*4096 = 262144
        int kj = i & 7;
        int l  = (i >> 3) & 63;
        int g  = (i >> 9) & 7;
        int ks = i >> 12;
        int mp = g * 16 + (l & 15);
        int kk = (l >> 4) * 8 + kj;
        int t = ks * 32 + kk;
        int m = mp >> 1;
        float ang = (float)((6.283185307179586476925287 / (double)NL) * (double)((m * t) & (NL - 1)));
        float val = (mp & 1) ? -sinf(ang) : cosf(ang);
        unsigned cb = __float_as_uint(val);
        ushort_t h = (ushort_t)(cb >> 16);
        float lo = val - __uint_as_float(cb & 0xffff0000u);
        Twh[i] = h;
        Twl[i] = (ushort_t)bf16_rne_bits(lo);
    } else {
        int i = (blk - 1024) * 256 + threadIdx.x;  // over 262144
        int j = i & 7;
        int l = (i >> 3) & 63;
        int f = (i >> 9) & 15;
        int ks = (i >> 13) & 3;
        int tt = i >> 15;
        int t = tt * 256 + f * 16 + (l & 15);
        int kk = ks * 32 + (l >> 4) * 8 + j;
        int x = kk >> 1;
        float ang = (float)((6.283185307179586476925287 / (double)NL) * (double)((t * x) & (NL - 1)));
        float val = (kk & 1) ? -sinf(ang) : cosf(ang);
        Ih[i] = __half_as_ushort(__float2half(val));
    }
}

// ---------------- K1: MFMA bf16 3-product DFT (R11/R13-proven path) + z==3 W-transpose -------
// z<3: Cpart[he, m'] = sum_t X[t, he] * Tw[t, m'] per (b, z, kq). Block 64he x 128m',
// BK=32, 32 ksteps, 4 waves, A via gld_lds XOR-swizzled, B frag-order hi/lo via gld_lds.
// z==3: 256 blocks transpose W -> Wtb16[h][x][e][o] (packed bf16 re|im<<16), 2 e each,
// reusing Bh/Bl LDS as scratch; these dispatch last and backfill the gemm tail.
__global__ __launch_bounds__(256, 3) void k_gemm(
    const float* __restrict__ q, const float* __restrict__ k, const float* __restrict__ v,
    const float* __restrict__ wr, const float* __restrict__ wi,
    const ushort_t* __restrict__ Twh, const ushort_t* __restrict__ Twl,
    float* __restrict__ Part, unsigned* __restrict__ Wtb16) {
    const int b  = blockIdx.y;       // 0..15
    const int z  = blockIdx.z;       // 0..3

    const int tid  = threadIdx.x;

    __shared__ float    As[2][32 * 64];   // raw fp32, he-swizzled, 8 KB each
    __shared__ ushort_t Bh[2][4096];      // frag-order bf16 hi, 8 KB each
    __shared__ ushort_t Bl[2][4096];      // frag-order bf16 lo, 8 KB each

    if (z == 3) {
        // ---- W transpose: idx -> (h, e-pair); o processed in halves of 32 ----
        const int idx = blockIdx.x * 16 + b;  // 0..255
        const int h = idx & 7, e2 = idx >> 3; // e2 0..31
        float* lr = (float*)&Bh[0][0];        // 32*68*4 = 8704 B  (<= 16384)
        float* li = (float*)&Bl[0][0];
        for (int u = 0; u < 2; ++u) {
            const int e = e2 * 2 + u;
            const float* rbase = wr + (size_t)(h * NE + e) * NE * NM;  // [o][x]
            const float* ibase = wi + (size_t)(h * NE + e) * NE * NM;
            for (int oh = 0; oh < 2; ++oh) {
#pragma unroll
                for (int j = 0; j < 2; ++j) {
                    int n = tid + j * 256;           // 512 f4
                    int o = n >> 4, x4 = n & 15;     // o 0..31
                    float4 r4 = ((const float4*)(rbase + (size_t)(oh * 32 + o) * NM))[x4];
                    float4 i4 = ((const float4*)(ibase + (size_t)(oh * 32 + o) * NM))[x4];
                    *((float4*)&lr[o * 68 + x4 * 4]) = r4;
                    *((float4*)&li[o * 68 + x4 * 4]) = i4;
                }
                __syncthreads();
#pragma unroll
                for (int j = 0; j < 8; ++j) {
                    int n = tid + j * 256;           // 2048 outputs
                    int x = n >> 5, o = n & 31;
                    unsigned hre = bf16_rne_bits(lr[o * 68 + x]);
                    unsigned him = bf16_rne_bits(li[o * 68 + x]);
                    Wtb16[((size_t)(h * NM + x) * NE + e) * NE + oh * 32 + o] =
                        hre | (him << 16);
                }
                __syncthreads();
            }
        }
        return;
    }

    const int bx = blockIdx.x & 7;   // he-group 0..7 (64 each)
    const int kq = blockIdx.x >> 3;  // K-half 0..1
    const float* __restrict__ in = (z == 0) ? q : ((z == 1) ? k : v);

    const int wid  = tid >> 6;
    const int lane = tid & 63;
    const int lr   = lane & 15;
    const int lg   = lane >> 4;
    const int wy   = wid >> 1;  // he-half -> +32
    const int wx   = wid & 1;   // m-half  -> +64
    const int he0  = bx * 64;
    const int fx   = lg & 1;    // A-swizzle bit (t bit3) for this lane's k-group

    f32x4 acc[2][4];
#pragma unroll
    for (int f = 0; f < 2; ++f)
#pragma unroll
        for (int j = 0; j < 4; ++j) acc[f][j] = (f32x4){0.f, 0.f, 0.f, 0.f};

    const size_t in_blk = ((size_t)b * NL + (size_t)kq * 1024) * NHE + he0;

#define STAGE(n, ksn)                                                                 \
    {                                                                                 \
        const ushort_t* gh = Twh + (size_t)(kq * 32 + (ksn)) * 4096;                  \
        const ushort_t* gl = Twl + (size_t)(kq * 32 + (ksn)) * 4096;                  \
        gld_lds16(gh + (size_t)tid * 8, &Bh[n][tid * 8]);                             \
        gld_lds16(gh + (size_t)(tid + 256) * 8, &Bh[n][(tid + 256) * 8]);             \
        gld_lds16(gl + (size_t)tid * 8, &Bl[n][tid * 8]);                             \
        gld_lds16(gl + (size_t)(tid + 256) * 8, &Bl[n][(tid + 256) * 8]);             \
        const float* ga = in + in_blk + (size_t)(ksn) * 32 * NHE;                     \
        _Pragma("unroll")                                                             \
        for (int p = 0; p < 2; ++p) {                                                 \
            int u = tid + p * 256;                                                    \
            int tloc = u >> 4, hc = u & 15;                                           \
            int hcs = hc ^ (((tloc >> 3) & 1) << 2);                                  \
            gld_lds16(ga + (size_t)tloc * NHE + hcs * 4, &As[n][u * 4]);              \
        }                                                                             \
    }

    STAGE(0, 0);

    int cur = 0;
    for (int ks = 0; ks < 32; ++ks) {
        __syncthreads();  // drains all gld_lds issued for buf `cur`
        if (ks + 1 < 32) STAGE(cur ^ 1, ks + 1);

        const float* ac = &As[cur][0];
        const ushort_t* bhc = &Bh[cur][0];
        const ushort_t* blc = &Bl[cur][0];

        short8 bh8[4], bl8[4];
#pragma unroll
        for (int j = 0; j < 4; ++j) {
            bh8[j] = *(const short8*)&bhc[((wx * 4 + j) * 64 + lane) * 8];
            bl8[j] = *(const short8*)&blc[((wx * 4 + j) * 64 + lane) * 8];
        }

#pragma unroll
        for (int f = 0; f < 2; ++f) {
            const int col = wy * 32 + ((f ^ fx) << 4) + lr;  // he ^ swizzle
            float xa[8];
#pragma unroll
            for (int j = 0; j < 8; ++j) xa[j] = ac[(8 * lg + j) * 64 + col];
            union { unsigned u[4]; short8 s; } uh, ul;
#pragma unroll
            for (int p = 0; p < 4; ++p) {
                unsigned b0 = __float_as_uint(xa[2 * p]);
                unsigned b1 = __float_as_uint(xa[2 * p + 1]);
                uh.u[p] = (b0 >> 16) | (b1 & 0xffff0000u);
                float l0 = xa[2 * p]     - __uint_as_float(b0 & 0xffff0000u);
                float l1 = xa[2 * p + 1] - __uint_as_float(b1 & 0xffff0000u);
                unsigned lw;
                asm("v_cvt_pk_bf16_f32 %0, %1, %2" : "=v"(lw) : "v"(l0), "v"(l1));
                ul.u[p] = lw;
            }
#pragma unroll
            for (int j = 0; j < 4; ++j) {
                acc[f][j] = __builtin_amdgcn_mfma_f32_16x16x32_bf16(uh.s, bh8[j], acc[f][j], 0, 0, 0);
                acc[f][j] = __builtin_amdgcn_mfma_f32_16x16x32_bf16(ul.s, bh8[j], acc[f][j], 0, 0, 0);
                acc[f][j] = __builtin_amdgcn_mfma_f32_16x16x32_bf16(uh.s, bl8[j], acc[f][j], 0, 0, 0);
            }
        }
        cur ^= 1;
    }
#undef STAGE

    // ---- epilogue: Part[(z*2+kq)][(b*512+he)][m'] ----
    float* pout = Part + (size_t)(z * 2 + kq) * 1048576;
#pragma unroll
    for (int f = 0; f < 2; ++f) {
#pragma unroll
        for (int j = 0; j < 4; ++j) {
            const int col = wx * 64 + j * 16 + lr;
#pragma unroll
            for (int r = 0; r < 4; ++r) {
                const int he = he0 + wy * 32 + f * 16 + 4 * lg + r;
                pout[((size_t)b * NHE + he) * 128 + col] = acc[f][j][r];
            }
        }
    }
}

// ---------------- K2: fused reduce + QK + tanh + QKV (512 threads) ----------------
__global__ __launch_bounds__(512) void k_qkqkv(
    const float* __restrict__ Part, float2* __restrict__ QKV) {
    const int bh = blockIdx.x;  // 0..127
    const int xh = blockIdx.y;  // 0..1
    const int tid = threadIdx.x;

    __shared__ float2 bufA[64 * 34];  // Qs, later Ps[32][66]
    __shared__ float2 bufB[64 * 66];  // Ks, later Vs

    const float4* P0 = (const float4*)Part;                 // Q kq=0
    const float4* P1 = P0 + 262144;                         // Q kq=1
    const float4* P2 = P0 + 2 * 262144;                     // K kq=0
    const float4* P3 = P0 + 3 * 262144;                     // K kq=1
    const float4* P4 = P0 + 4 * 262144;                     // V kq=0
    const float4* P5 = P0 + 5 * 262144;                     // V kq=1
    const size_t fb = (size_t)bh * 2048;                    // float4 base of this bh

#pragma unroll
    for (int j = 0; j < 2; ++j) {
        int n = tid + j * 512;  // 1024 f4
        int e = n >> 4, c = n & 15;
        float4 a = P0[fb + e * 32 + xh * 16 + c];
        float4 b = P1[fb + e * 32 + xh * 16 + c];
        *((float4*)&bufA[e * 34 + c * 2]) =
            make_float4(a.x + b.x, a.y + b.y, a.z + b.z, a.w + b.w);
    }
#pragma unroll
    for (int j = 0; j < 4; ++j) {
        int n = tid + j * 512;  // 2048 f4
        int e = n >> 5, c = n & 31;
        float4 a = P2[fb + e * 32 + c];
        float4 b = P3[fb + e * 32 + c];
        *((float4*)&bufB[e * 66 + c * 2]) =
            make_float4(a.x + b.x, a.y + b.y, a.z + b.z, a.w + b.w);
    }
    __syncthreads();

    // ---- qk: thread tile 2x * 2y over [32x][64y] ----
    const int yq = tid & 31, xq = tid >> 5;  // xq 0..15 -> x0 = xq*2
    const int x0 = xq * 2;
    float accr[2][2], acci[2][2];
#pragma unroll
    for (int i = 0; i < 2; ++i)
#pragma unroll
        for (int j = 0; j < 2; ++j) { accr[i][j] = 0.f; acci[i][j] = 0.f; }

    for (int e = 0; e < 64; ++e) {
        float4 qa = *((float4*)&bufA[e * 34 + x0]);
        float4 kk = *((float4*)&bufB[e * 66 + yq * 2]);
        float qr[2] = {qa.x, qa.z};
        float qi[2] = {qa.y, qa.w};
        float kr[2] = {kk.x, kk.z};
        float ki[2] = {kk.y, kk.w};
#pragma unroll
        for (int i = 0; i < 2; ++i) {
#pragma unroll
            for (int j = 0; j < 2; ++j) {
                accr[i][j] += qr[i] * kr[j] - qi[i] * ki[j];
                acci[i][j] += qr[i] * ki[j] + qi[i] * kr[j];
            }
        }
    }
    __syncthreads();  // all reads of Qs/Ks done; safe to overwrite bufA/bufB

    float2* Ps = bufA;
#pragma unroll
    for (int i = 0; i < 2; ++i) {
        float4 sv = make_float4(tanhf(accr[i][0]), tanhf(acci[i][0]),
                                tanhf(accr[i][1]), tanhf(acci[i][1]));
        *((float4*)&Ps[(x0 + i) * 66 + yq * 2]) = sv;
    }
#pragma unroll
    for (int j = 0; j < 4; ++j) {
        int n = tid + j * 512;
        int e = n >> 5, c = n & 31;
        float4 a = P4[fb + e * 32 + c];
        float4 b = P5[fb + e * 32 + c];
        *((float4*)&bufB[e * 66 + c * 2]) =
            make_float4(a.x + b.x, a.y + b.y, a.z + b.z, a.w + b.w);
    }
    __syncthreads();

    // ---- qkv: thread tile 1e * 4x over [64e][32x] ----
    const int xq2 = tid & 7, eq2 = tid >> 3;  // eq2 0..63
    const int x2 = xq2 * 4;
    float br[4], bi[4];
#pragma unroll
    for (int j = 0; j < 4; ++j) { br[j] = 0.f; bi[j] = 0.f; }

    for (int yy = 0; yy < 64; ++yy) {
        float2 v0 = bufB[eq2 * 66 + yy];
        float2 p0 = Ps[(x2 + 0) * 66 + yy];
        float2 p1 = Ps[(x2 + 1) * 66 + yy];
        float2 p2 = Ps[(x2 + 2) * 66 + yy];
        float2 p3 = Ps[(x2 + 3) * 66 + yy];
        float pr[4] = {p0.x, p1.x, p2.x, p3.x};
        float pi[4] = {p0.y, p1.y, p2.y, p3.y};
#pragma unroll
        for (int j = 0; j < 4; ++j) {
            br[j] += v0.x * pr[j] - v0.y * pi[j];
            bi[j] += v0.x * pi[j] + v0.y * pr[j];
        }
    }
    {
        float2* obase = QKV + (size_t)bh * 4096 + eq2 * 64 + xh * 32 + x2;
        float4 s0 = make_float4(br[0], bi[0], br[1], bi[1]);
        float4 s1 = make_float4(br[2], bi[2], br[3], bi[3]);
        ((float4*)obase)[0] = s0;
        ((float4*)obase)[1] = s1;
    }
}

// ---------------- K4: QKVW[o,x] = sum_e QKV[e,x]*W[e,o,x] (bf16 W), irfft scale x1024 --------
__global__ __launch_bounds__(256) void k_qkvw(
    const float2* __restrict__ QKV, const unsigned* __restrict__ Wtb16,
    float2* __restrict__ QKVWs) {
    const int x = blockIdx.x, h = blockIdx.y;
    const int tid = threadIdx.x;
    const int o = tid & 63, bq = tid >> 6;
    float accr[4], acci[4];
#pragma unroll
    for (int j = 0; j < 4; ++j) { accr[j] = 0.f; acci[j] = 0.f; }

    const unsigned* wbase = Wtb16 + (size_t)(h * NM + x) * NE * NE + o;
#pragma unroll 8
    for (int e = 0; e < 64; ++e) {
        unsigned w = wbase[(size_t)e * NE];
        float wre = __uint_as_float(w << 16);
        float wim = __uint_as_float(w & 0xffff0000u);
#pragma unroll
        for (int j = 0; j < 4; ++j) {
            int b = bq * 4 + j;
            float2 a = QKV[((size_t)(b * NH + h) * NE + e) * NM + x];
            accr[j] += a.x * wre - a.y * wim;
            acci[j] += a.x * wim + a.y * wre;
        }
    }
    // (1/NL or 2/NL) * 1024 (exact powers of 2); undone by /1024 in k_idft epilogue
    const float sc = (x == 0) ? 0.5f : 1.0f;
#pragma unroll
    for (int j = 0; j < 4; ++j) {
        int b = bq * 4 + j;
        QKVWs[((size_t)(b * NH + h) * NM + x) * NE + o] =
            make_float2(accr[j] * sc, acci[j] * sc);
    }
}

// ---------------- K5: MFMA fp16 1-product iDFT + transpose to [B,L,H,O] ----------------
__global__ __launch_bounds__(256, 3) void k_idft(
    const float2* __restrict__ QKVWs, const ushort_t* __restrict__ Ih,
    float* __restrict__ yout) {
    const int tt = blockIdx.x;   // 0..7
    const int bh = blockIdx.y;   // 0..127
    const int b = bh >> 3, h = bh & 7;
    const int tid = threadIdx.x;
    const int wid = tid >> 6;
    const int lane = tid & 63;
    const int lr = lane & 15;
    const int lg = lane >> 4;

    __shared__ ushort_t Ta[8192];   // table tile: [16 frag][64 lane][8]
    __shared__ unsigned Xs[4096];   // X fp16 pairs, frag order [4ks][4jn][64lane][4]

    const float2* xb = QKVWs + (size_t)bh * 4096;
#pragma unroll
    for (int r = 0; r < 16; ++r) {
        int i = tid + r * 256;
        int x = i >> 6, o = i & 63;
        float2 val = xb[i];
        int ks = x >> 4;
        int lane2 = (((x & 15) >> 2) << 4) | (o & 15);
        int jn = o >> 4;
        unsigned pk = (unsigned)__half_as_ushort(__float2half(val.x)) |
                      ((unsigned)__half_as_ushort(__float2half(val.y)) << 16);
        Xs[((ks * 4 + jn) * 64 + lane2) * 4 + (x & 3)] = pk;
    }
    {
        const ushort_t* gh = Ih + (size_t)(tt * 4) * 8192;
#pragma unroll
        for (int p = 0; p < 4; ++p)
            gld_lds16(gh + (size_t)(tid + p * 256) * 8, &Ta[(tid + p * 256) * 8]);
    }
    __syncthreads();

    f32x4 acc[4][4];
#pragma unroll
    for (int m = 0; m < 4; ++m)
#pragma unroll
        for (int n = 0; n < 4; ++n) acc[m][n] = (f32x4){0.f, 0.f, 0.f, 0.f};

    const ushort_t* XsS = (const ushort_t*)Xs;
    for (int ks = 0; ks < 4; ++ks) {
        half8 ah[4], bx_[4];
#pragma unroll
        for (int m = 0; m < 4; ++m)
            ah[m] = *(const half8*)&Ta[((wid * 4 + m) * 64 + lane) * 8];
#pragma unroll
        for (int n = 0; n < 4; ++n)
            bx_[n] = *(const half8*)&XsS[((ks * 4 + n) * 64 + lane) * 8];
#pragma unroll
        for (int m = 0; m < 4; ++m)
#pragma unroll
            for (int n = 0; n < 4; ++n)
                acc[m][n] = __builtin_amdgcn_mfma_f32_16x16x32_f16(ah[m], bx_[n], acc[m][n], 0, 0, 0);
        if (ks < 3) {
            __syncthreads();
            const ushort_t* gh = Ih + (size_t)(tt * 4 + ks + 1) * 8192;
#pragma unroll
            for (int p = 0; p < 4; ++p)
                gld_lds16(gh + (size_t)(tid + p * 256) * 8, &Ta[(tid + p * 256) * 8]);
            __syncthreads();
        }
    }

    const int t0 = tt * 256 + wid * 64;
    const float inv = 1.f / 1024.f;
#pragma unroll
    for (int m = 0; m < 4; ++m) {
#pragma unroll
        for (int n = 0; n < 4; ++n) {
            const int o = n * 16 + lr;
#pragma unroll
            for (int r = 0; r < 4; ++r) {
                const int t = t0 + m * 16 + lg * 4 + r;
                yout[(((size_t)b * NL + t) * NH + h) * NE + o] = acc[m][n][r] * inv;
            }
        }
    }
}

extern "C" void kernel_launch(void* const* d_in, const int* in_sizes, int n_in,
                              void* d_out, int out_size, void* d_ws, size_t ws_size,
                              hipStream_t stream) {
    const float* q  = (const float*)d_in[0];
    const float* k  = (const float*)d_in[1];
    const float* v  = (const float*)d_in[2];
    const float* wr = (const float*)d_in[3];
    const float* wi = (const float*)d_in[4];
    float* out = (float*)d_out;

    // workspace layout (bytes). Wtb16 fills the 6.3-14.7 MB gap (no Part overlay).
    char* w = (char*)d_ws;
    ushort_t* Twh   = (ushort_t*)w;                     //   524,288 B (bf16 hi DFT table)
    ushort_t* Twl   = (ushort_t*)(w + 524288);          //   524,288 B (bf16 lo DFT table)
    ushort_t* Ih    = (ushort_t*)(w + 1048576);         //   524,288 B (fp16 iDFT table)
    float2*   QKV   = (float2*)(w + 2097152);           // 4,194,304 B
    unsigned* Wtb16 = (unsigned*)(w + 6291456);         // 8,388,608 B (packed bf16 W)
    float*    Part  = (float*)(w + 14680064);           // 25,165,824 B (6 x 1M floats)
    float2*   QKVWs = (float2*)(w + 39845888);          // 4,194,304 B
    // total = 44,040,192 B

    hipLaunchKernelGGL(k_tables, dim3(2048), dim3(256), 0, stream, Twh, Twl, Ih);
    hipLaunchKernelGGL(k_gemm, dim3(16, 16, 4), dim3(256), 0, stream,
                       q, k, v, wr, wi, Twh, Twl, Part, Wtb16);
    hipLaunchKernelGGL(k_qkqkv, dim3(128, 2), dim3(512), 0, stream, Part, QKV);
    hipLaunchKernelGGL(k_qkvw, dim3(64, 8), dim3(256), 0, stream, QKV, Wtb16, QKVWs);
    hipLaunchKernelGGL(k_idft, dim3(8, 128), dim3(256), 0, stream, QKVWs, Ih, out);
}

// Round 15
// 133.896 us; speedup vs baseline: 1.3363x; 1.3363x over previous
//
#include <hip/hip_runtime.h>
#include <hip/hip_fp16.h>
#include <math.h>

// FourierCrossAttention: B=16, L=S=2048, H=8, E=O=64, M=64 (first 64 rfft modes)
// Pipeline: tables(fused) -> MFMA bf16 3-product DFT [K-split x2] -> fused(reduce+QK+tanh+QKV)
//           -> Wt(packed bf16) -> QKVW(x1024) -> MFMA fp16 1-product iDFT (/1024)
// R15 = R13 (144.7us proven) + ONLY the bf16-W packing (numerics proven in R14):
// k_wt writes packed bf16 re|im (halves W traffic both ways); k_qkvw unpacks, default unroll.

#define NB 16
#define NL 2048
#define NH 8
#define NE 64
#define NM 64
#define NHE 512  // H*E

typedef unsigned short ushort_t;
typedef __attribute__((ext_vector_type(8))) short short8;
typedef __attribute__((ext_vector_type(8))) _Float16 half8;
typedef __attribute__((ext_vector_type(4))) float f32x4;

__device__ inline void gld_lds16(const void* g, void* l) {
    __builtin_amdgcn_global_load_lds((const __attribute__((address_space(1))) unsigned int*)g,
                                     (__attribute__((address_space(3))) unsigned int*)l, 16, 0, 0);
}

__device__ inline unsigned bf16_rne_bits(float v) {
    unsigned b = __float_as_uint(v);
    return (b + 0x7fffu + ((b >> 16) & 1u)) >> 16;
}

// ---------------- K0: fused twiddle tables (DFT hi/lo bf16 + iDFT fp16), frag order ----------
__global__ __launch_bounds__(256) void k_tables(ushort_t* __restrict__ Twh,
                                                ushort_t* __restrict__ Twl,
                                                ushort_t* __restrict__ Ih) {
    const int blk = blockIdx.x;
    if (blk < 1024) {
        int i = blk * 256 + threadIdx.x;  // over 64*4096 = 262144
        int kj = i & 7;
        int l  = (i >> 3) & 63;
        int g  = (i >> 9) & 7;
        int ks = i >> 12;
        int mp = g * 16 + (l & 15);
        int kk = (l >> 4) * 8 + kj;
        int t = ks * 32 + kk;
        int m = mp >> 1;
        float ang = (float)((6.283185307179586476925287 / (double)NL) * (double)((m * t) & (NL - 1)));
        float val = (mp & 1) ? -sinf(ang) : cosf(ang);
        unsigned cb = __float_as_uint(val);
        ushort_t h = (ushort_t)(cb >> 16);
        float lo = val - __uint_as_float(cb & 0xffff0000u);
        Twh[i] = h;
        Twl[i] = (ushort_t)bf16_rne_bits(lo);
    } else {
        int i = (blk - 1024) * 256 + threadIdx.x;  // over 262144
        int j = i & 7;
        int l = (i >> 3) & 63;
        int f = (i >> 9) & 15;
        int ks = (i >> 13) & 3;
        int tt = i >> 15;
        int t = tt * 256 + f * 16 + (l & 15);
        int kk = ks * 32 + (l >> 4) * 8 + j;
        int x = kk >> 1;
        float ang = (float)((6.283185307179586476925287 / (double)NL) * (double)((t * x) & (NL - 1)));
        float val = (kk & 1) ? -sinf(ang) : cosf(ang);
        Ih[i] = __half_as_ushort(__float2half(val));
    }
}

// ---------------- K1: MFMA bf16 3-product DFT (R11/R13-proven verbatim), K-split x2 -----------
// Cpart[he, m'] = sum_t X[t, he] * Tw[t, m'] per (b, z, kq). Block 64he x 128m',
// BK=32, 32 ksteps, 4 waves (2wy x 2wx), wave tile 32x64 (2x4 acc of 16x16).
// A: raw fp32 [32t][64he] via gld_lds, XOR-swizzled; B: frag-order bf16 hi/lo via gld_lds.
__global__ __launch_bounds__(256, 3) void k_gemm(
    const float* __restrict__ q, const float* __restrict__ k, const float* __restrict__ v,
    const ushort_t* __restrict__ Twh, const ushort_t* __restrict__ Twl,
    float* __restrict__ Part) {
    const int bx = blockIdx.x & 7;   // he-group 0..7 (64 each)
    const int kq = blockIdx.x >> 3;  // K-half 0..1
    const int b  = blockIdx.y;       // 0..15
    const int z  = blockIdx.z;       // 0..2
    const float* __restrict__ in = (z == 0) ? q : ((z == 1) ? k : v);

    const int tid  = threadIdx.x;
    const int wid  = tid >> 6;
    const int lane = tid & 63;
    const int lr   = lane & 15;
    const int lg   = lane >> 4;
    const int wy   = wid >> 1;  // he-half -> +32
    const int wx   = wid & 1;   // m-half  -> +64
    const int he0  = bx * 64;
    const int fx   = lg & 1;    // A-swizzle bit (t bit3) for this lane's k-group

    __shared__ float    As[2][32 * 64];   // raw fp32, he-swizzled, 8 KB each
    __shared__ ushort_t Bh[2][4096];      // frag-order bf16 hi, 8 KB each
    __shared__ ushort_t Bl[2][4096];      // frag-order bf16 lo, 8 KB each

    f32x4 acc[2][4];
#pragma unroll
    for (int f = 0; f < 2; ++f)
#pragma unroll
        for (int j = 0; j < 4; ++j) acc[f][j] = (f32x4){0.f, 0.f, 0.f, 0.f};

    const size_t in_blk = ((size_t)b * NL + (size_t)kq * 1024) * NHE + he0;

#define STAGE(n, ksn)                                                                 \
    {                                                                                 \
        const ushort_t* gh = Twh + (size_t)(kq * 32 + (ksn)) * 4096;                  \
        const ushort_t* gl = Twl + (size_t)(kq * 32 + (ksn)) * 4096;                  \
        gld_lds16(gh + (size_t)tid * 8, &Bh[n][tid * 8]);                             \
        gld_lds16(gh + (size_t)(tid + 256) * 8, &Bh[n][(tid + 256) * 8]);             \
        gld_lds16(gl + (size_t)tid * 8, &Bl[n][tid * 8]);                             \
        gld_lds16(gl + (size_t)(tid + 256) * 8, &Bl[n][(tid + 256) * 8]);             \
        const float* ga = in + in_blk + (size_t)(ksn) * 32 * NHE;                     \
        _Pragma("unroll")                                                             \
        for (int p = 0; p < 2; ++p) {                                                 \
            int u = tid + p * 256;                                                    \
            int tloc = u >> 4, hc = u & 15;                                           \
            int hcs = hc ^ (((tloc >> 3) & 1) << 2);                                  \
            gld_lds16(ga + (size_t)tloc * NHE + hcs * 4, &As[n][u * 4]);              \
        }                                                                             \
    }

    STAGE(0, 0);

    int cur = 0;
    for (int ks = 0; ks < 32; ++ks) {
        __syncthreads();  // drains all gld_lds issued for buf `cur`
        if (ks + 1 < 32) STAGE(cur ^ 1, ks + 1);

        const float* ac = &As[cur][0];
        const ushort_t* bhc = &Bh[cur][0];
        const ushort_t* blc = &Bl[cur][0];

        short8 bh8[4], bl8[4];
#pragma unroll
        for (int j = 0; j < 4; ++j) {
            bh8[j] = *(const short8*)&bhc[((wx * 4 + j) * 64 + lane) * 8];
            bl8[j] = *(const short8*)&blc[((wx * 4 + j) * 64 + lane) * 8];
        }

#pragma unroll
        for (int f = 0; f < 2; ++f) {
            const int col = wy * 32 + ((f ^ fx) << 4) + lr;  // he ^ swizzle
            float xa[8];
#pragma unroll
            for (int j = 0; j < 8; ++j) xa[j] = ac[(8 * lg + j) * 64 + col];
            union { unsigned u[4]; short8 s; } uh, ul;
#pragma unroll
            for (int p = 0; p < 4; ++p) {
                unsigned b0 = __float_as_uint(xa[2 * p]);
                unsigned b1 = __float_as_uint(xa[2 * p + 1]);
                uh.u[p] = (b0 >> 16) | (b1 & 0xffff0000u);
                float l0 = xa[2 * p]     - __uint_as_float(b0 & 0xffff0000u);
                float l1 = xa[2 * p + 1] - __uint_as_float(b1 & 0xffff0000u);
                unsigned lw;
                asm("v_cvt_pk_bf16_f32 %0, %1, %2" : "=v"(lw) : "v"(l0), "v"(l1));
                ul.u[p] = lw;
            }
#pragma unroll
            for (int j = 0; j < 4; ++j) {
                acc[f][j] = __builtin_amdgcn_mfma_f32_16x16x32_bf16(uh.s, bh8[j], acc[f][j], 0, 0, 0);
                acc[f][j] = __builtin_amdgcn_mfma_f32_16x16x32_bf16(ul.s, bh8[j], acc[f][j], 0, 0, 0);
                acc[f][j] = __builtin_amdgcn_mfma_f32_16x16x32_bf16(uh.s, bl8[j], acc[f][j], 0, 0, 0);
            }
        }
        cur ^= 1;
    }
#undef STAGE

    // ---- epilogue: Part[(z*2+kq)][(b*512+he)][m'] ----
    float* pout = Part + (size_t)(z * 2 + kq) * 1048576;
#pragma unroll
    for (int f = 0; f < 2; ++f) {
#pragma unroll
        for (int j = 0; j < 4; ++j) {
            const int col = wx * 64 + j * 16 + lr;
#pragma unroll
            for (int r = 0; r < 4; ++r) {
                const int he = he0 + wy * 32 + f * 16 + 4 * lg + r;
                pout[((size_t)b * NHE + he) * 128 + col] = acc[f][j][r];
            }
        }
    }
}

// ---------------- K2: fused reduce + QK + tanh + QKV (512 threads) ----------------
__global__ __launch_bounds__(512) void k_qkqkv(
    const float* __restrict__ Part, float2* __restrict__ QKV) {
    const int bh = blockIdx.x;  // 0..127
    const int xh = blockIdx.y;  // 0..1
    const int tid = threadIdx.x;

    __shared__ float2 bufA[64 * 34];  // Qs, later Ps[32][66]
    __shared__ float2 bufB[64 * 66];  // Ks, later Vs

    const float4* P0 = (const float4*)Part;                 // Q kq=0
    const float4* P1 = P0 + 262144;                         // Q kq=1
    const float4* P2 = P0 + 2 * 262144;                     // K kq=0
    const float4* P3 = P0 + 3 * 262144;                     // K kq=1
    const float4* P4 = P0 + 4 * 262144;                     // V kq=0
    const float4* P5 = P0 + 5 * 262144;                     // V kq=1
    const size_t fb = (size_t)bh * 2048;                    // float4 base of this bh

#pragma unroll
    for (int j = 0; j < 2; ++j) {
        int n = tid + j * 512;  // 1024 f4
        int e = n >> 4, c = n & 15;
        float4 a = P0[fb + e * 32 + xh * 16 + c];
        float4 b = P1[fb + e * 32 + xh * 16 + c];
        *((float4*)&bufA[e * 34 + c * 2]) =
            make_float4(a.x + b.x, a.y + b.y, a.z + b.z, a.w + b.w);
    }
#pragma unroll
    for (int j = 0; j < 4; ++j) {
        int n = tid + j * 512;  // 2048 f4
        int e = n >> 5, c = n & 31;
        float4 a = P2[fb + e * 32 + c];
        float4 b = P3[fb + e * 32 + c];
        *((float4*)&bufB[e * 66 + c * 2]) =
            make_float4(a.x + b.x, a.y + b.y, a.z + b.z, a.w + b.w);
    }
    __syncthreads();

    // ---- qk: thread tile 2x * 2y over [32x][64y] ----
    const int yq = tid & 31, xq = tid >> 5;  // xq 0..15 -> x0 = xq*2
    const int x0 = xq * 2;
    float accr[2][2], acci[2][2];
#pragma unroll
    for (int i = 0; i < 2; ++i)
#pragma unroll
        for (int j = 0; j < 2; ++j) { accr[i][j] = 0.f; acci[i][j] = 0.f; }

    for (int e = 0; e < 64; ++e) {
        float4 qa = *((float4*)&bufA[e * 34 + x0]);
        float4 kk = *((float4*)&bufB[e * 66 + yq * 2]);
        float qr[2] = {qa.x, qa.z};
        float qi[2] = {qa.y, qa.w};
        float kr[2] = {kk.x, kk.z};
        float ki[2] = {kk.y, kk.w};
#pragma unroll
        for (int i = 0; i < 2; ++i) {
#pragma unroll
            for (int j = 0; j < 2; ++j) {
                accr[i][j] += qr[i] * kr[j] - qi[i] * ki[j];
                acci[i][j] += qr[i] * ki[j] + qi[i] * kr[j];
            }
        }
    }
    __syncthreads();  // all reads of Qs/Ks done; safe to overwrite bufA/bufB

    float2* Ps = bufA;
#pragma unroll
    for (int i = 0; i < 2; ++i) {
        float4 sv = make_float4(tanhf(accr[i][0]), tanhf(acci[i][0]),
                                tanhf(accr[i][1]), tanhf(acci[i][1]));
        *((float4*)&Ps[(x0 + i) * 66 + yq * 2]) = sv;
    }
#pragma unroll
    for (int j = 0; j < 4; ++j) {
        int n = tid + j * 512;
        int e = n >> 5, c = n & 31;
        float4 a = P4[fb + e * 32 + c];
        float4 b = P5[fb + e * 32 + c];
        *((float4*)&bufB[e * 66 + c * 2]) =
            make_float4(a.x + b.x, a.y + b.y, a.z + b.z, a.w + b.w);
    }
    __syncthreads();

    // ---- qkv: thread tile 1e * 4x over [64e][32x] ----
    const int xq2 = tid & 7, eq2 = tid >> 3;  // eq2 0..63
    const int x2 = xq2 * 4;
    float br[4], bi[4];
#pragma unroll
    for (int j = 0; j < 4; ++j) { br[j] = 0.f; bi[j] = 0.f; }

    for (int yy = 0; yy < 64; ++yy) {
        float2 v0 = bufB[eq2 * 66 + yy];
        float2 p0 = Ps[(x2 + 0) * 66 + yy];
        float2 p1 = Ps[(x2 + 1) * 66 + yy];
        float2 p2 = Ps[(x2 + 2) * 66 + yy];
        float2 p3 = Ps[(x2 + 3) * 66 + yy];
        float pr[4] = {p0.x, p1.x, p2.x, p3.x};
        float pi[4] = {p0.y, p1.y, p2.y, p3.y};
#pragma unroll
        for (int j = 0; j < 4; ++j) {
            br[j] += v0.x * pr[j] - v0.y * pi[j];
            bi[j] += v0.x * pi[j] + v0.y * pr[j];
        }
    }
    {
        float2* obase = QKV + (size_t)bh * 4096 + eq2 * 64 + xh * 32 + x2;
        float4 s0 = make_float4(br[0], bi[0], br[1], bi[1]);
        float4 s1 = make_float4(br[2], bi[2], br[3], bi[3]);
        ((float4*)obase)[0] = s0;
        ((float4*)obase)[1] = s1;
    }
}

// ---------------- K4a: transpose W -> Wtb16[h][x][e][o] (packed bf16 re|im<<16) -------------
__global__ __launch_bounds__(256) void k_wt(
    const float* __restrict__ wr, const float* __restrict__ wi,
    unsigned* __restrict__ Wtb16) {
    const int e = blockIdx.x, h = blockIdx.y;
    const int tid = threadIdx.x;
    __shared__ float lr[64 * 68];
    __shared__ float li[64 * 68];
    const float* rbase = wr + (size_t)(h * NE + e) * NE * NM;
    const float* ibase = wi + (size_t)(h * NE + e) * NE * NM;
#pragma unroll
    for (int j = 0; j < 4; ++j) {
        int n = tid + j * 256;
        int o = n >> 4, x4 = n & 15;
        float4 r4 = ((const float4*)(rbase + o * NM))[x4];
        float4 i4 = ((const float4*)(ibase + o * NM))[x4];
        *((float4*)&lr[o * 68 + x4 * 4]) = r4;
        *((float4*)&li[o * 68 + x4 * 4]) = i4;
    }
    __syncthreads();
#pragma unroll
    for (int j = 0; j < 16; ++j) {
        int n = tid + j * 256;
        int x = n >> 6, o = n & 63;
        unsigned hre = bf16_rne_bits(lr[o * 68 + x]);
        unsigned him = bf16_rne_bits(li[o * 68 + x]);
        Wtb16[((size_t)(h * NM + x) * NE + e) * NE + o] = hre | (him << 16);
    }
}

// ---------------- K4: QKVW[o,x] = sum_e QKV[e,x]*W[e,o,x] (bf16 W), irfft scale x1024 --------
__global__ __launch_bounds__(256) void k_qkvw(
    const float2* __restrict__ QKV, const unsigned* __restrict__ Wtb16,
    float2* __restrict__ QKVWs) {
    const int x = blockIdx.x, h = blockIdx.y;
    const int tid = threadIdx.x;
    const int o = tid & 63, bq = tid >> 6;
    float accr[4], acci[4];
#pragma unroll
    for (int j = 0; j < 4; ++j) { accr[j] = 0.f; acci[j] = 0.f; }

    const unsigned* wbase = Wtb16 + (size_t)(h * NM + x) * NE * NE + o;
    for (int e = 0; e < 64; ++e) {
        unsigned w = wbase[(size_t)e * NE];
        float wre = __uint_as_float(w << 16);
        float wim = __uint_as_float(w & 0xffff0000u);
#pragma unroll
        for (int j = 0; j < 4; ++j) {
            int b = bq * 4 + j;
            float2 a = QKV[((size_t)(b * NH + h) * NE + e) * NM + x];
            accr[j] += a.x * wre - a.y * wim;
            acci[j] += a.x * wim + a.y * wre;
        }
    }
    // (1/NL or 2/NL) * 1024 (exact powers of 2); undone by /1024 in k_idft epilogue
    const float sc = (x == 0) ? 0.5f : 1.0f;
#pragma unroll
    for (int j = 0; j < 4; ++j) {
        int b = bq * 4 + j;
        QKVWs[((size_t)(b * NH + h) * NM + x) * NE + o] =
            make_float2(accr[j] * sc, acci[j] * sc);
    }
}

// ---------------- K5: MFMA fp16 1-product iDFT + transpose to [B,L,H,O] ----------------
__global__ __launch_bounds__(256, 3) void k_idft(
    const float2* __restrict__ QKVWs, const ushort_t* __restrict__ Ih,
    float* __restrict__ yout) {
    const int tt = blockIdx.x;   // 0..7
    const int bh = blockIdx.y;   // 0..127
    const int b = bh >> 3, h = bh & 7;
    const int tid = threadIdx.x;
    const int wid = tid >> 6;
    const int lane = tid & 63;
    const int lr = lane & 15;
    const int lg = lane >> 4;

    __shared__ ushort_t Ta[8192];   // table tile: [16 frag][64 lane][8]
    __shared__ unsigned Xs[4096];   // X fp16 pairs, frag order [4ks][4jn][64lane][4]

    const float2* xb = QKVWs + (size_t)bh * 4096;
#pragma unroll
    for (int r = 0; r < 16; ++r) {
        int i = tid + r * 256;
        int x = i >> 6, o = i & 63;
        float2 val = xb[i];
        int ks = x >> 4;
        int lane2 = (((x & 15) >> 2) << 4) | (o & 15);
        int jn = o >> 4;
        unsigned pk = (unsigned)__half_as_ushort(__float2half(val.x)) |
                      ((unsigned)__half_as_ushort(__float2half(val.y)) << 16);
        Xs[((ks * 4 + jn) * 64 + lane2) * 4 + (x & 3)] = pk;
    }
    {
        const ushort_t* gh = Ih + (size_t)(tt * 4) * 8192;
#pragma unroll
        for (int p = 0; p < 4; ++p)
            gld_lds16(gh + (size_t)(tid + p * 256) * 8, &Ta[(tid + p * 256) * 8]);
    }
    __syncthreads();

    f32x4 acc[4][4];
#pragma unroll
    for (int m = 0; m < 4; ++m)
#pragma unroll
        for (int n = 0; n < 4; ++n) acc[m][n] = (f32x4){0.f, 0.f, 0.f, 0.f};

    const ushort_t* XsS = (const ushort_t*)Xs;
    for (int ks = 0; ks < 4; ++ks) {
        half8 ah[4], bx_[4];
#pragma unroll
        for (int m = 0; m < 4; ++m)
            ah[m] = *(const half8*)&Ta[((wid * 4 + m) * 64 + lane) * 8];
#pragma unroll
        for (int n = 0; n < 4; ++n)
            bx_[n] = *(const half8*)&XsS[((ks * 4 + n) * 64 + lane) * 8];
#pragma unroll
        for (int m = 0; m < 4; ++m)
#pragma unroll
            for (int n = 0; n < 4; ++n)
                acc[m][n] = __builtin_amdgcn_mfma_f32_16x16x32_f16(ah[m], bx_[n], acc[m][n], 0, 0, 0);
        if (ks < 3) {
            __syncthreads();
            const ushort_t* gh = Ih + (size_t)(tt * 4 + ks + 1) * 8192;
#pragma unroll
            for (int p = 0; p < 4; ++p)
                gld_lds16(gh + (size_t)(tid + p * 256) * 8, &Ta[(tid + p * 256) * 8]);
            __syncthreads();
        }
    }

    const int t0 = tt * 256 + wid * 64;
    const float inv = 1.f / 1024.f;
#pragma unroll
    for (int m = 0; m < 4; ++m) {
#pragma unroll
        for (int n = 0; n < 4; ++n) {
            const int o = n * 16 + lr;
#pragma unroll
            for (int r = 0; r < 4; ++r) {
                const int t = t0 + m * 16 + lg * 4 + r;
                yout[(((size_t)b * NL + t) * NH + h) * NE + o] = acc[m][n][r] * inv;
            }
        }
    }
}

extern "C" void kernel_launch(void* const* d_in, const int* in_sizes, int n_in,
                              void* d_out, int out_size, void* d_ws, size_t ws_size,
                              hipStream_t stream) {
    const float* q  = (const float*)d_in[0];
    const float* k  = (const float*)d_in[1];
    const float* v  = (const float*)d_in[2];
    const float* wr = (const float*)d_in[3];
    const float* wi = (const float*)d_in[4];
    float* out = (float*)d_out;

    // workspace layout (bytes). Wtb16 fills the 6.3-14.7 MB gap (no Part overlay).
    char* w = (char*)d_ws;
    ushort_t* Twh   = (ushort_t*)w;                     //   524,288 B (bf16 hi DFT table)
    ushort_t* Twl   = (ushort_t*)(w + 524288);          //   524,288 B (bf16 lo DFT table)
    ushort_t* Ih    = (ushort_t*)(w + 1048576);         //   524,288 B (fp16 iDFT table)
    float2*   QKV   = (float2*)(w + 2097152);           // 4,194,304 B
    unsigned* Wtb16 = (unsigned*)(w + 6291456);         // 8,388,608 B (packed bf16 W)
    float*    Part  = (float*)(w + 14680064);           // 25,165,824 B (6 x 1M floats)
    float2*   QKVWs = (float2*)(w + 39845888);          // 4,194,304 B
    // total = 44,040,192 B

    hipLaunchKernelGGL(k_tables, dim3(2048), dim3(256), 0, stream, Twh, Twl, Ih);
    hipLaunchKernelGGL(k_gemm, dim3(16, 16, 3), dim3(256), 0, stream,
                       q, k, v, Twh, Twl, Part);
    hipLaunchKernelGGL(k_qkqkv, dim3(128, 2), dim3(512), 0, stream, Part, QKV);
    hipLaunchKernelGGL(k_wt, dim3(64, 8), dim3(256), 0, stream, wr, wi, Wtb16);
    hipLaunchKernelGGL(k_qkvw, dim3(64, 8), dim3(256), 0, stream, QKV, Wtb16, QKVWs);
    hipLaunchKernelGGL(k_idft, dim3(8, 128), dim3(256), 0, stream, QKVWs, Ih, out);
}